// Round 5
// baseline (10097.871 us; speedup 1.0000x reference)
//
#include <hip/hip_runtime.h>
#include <math.h>

#define NT 512        // time steps
#define NB 512        // batch
#define HID 128
#define NIN 10
#define NC 10         // memory cells
#define CW 20         // cell width
#define NIF 88        // interface size
#define NOUT 10
#define GB 2          // batches per workgroup
#define BLK 1024      // threads per block (16 waves, 1 block/CU -> 128 VGPR cap by HW)

typedef _Float16 h1;
typedef _Float16 h2 __attribute__((ext_vector_type(2)));

__device__ __forceinline__ float sigf(float x) { return 1.0f / (1.0f + expf(-x)); }
// jax.nn.softplus == logaddexp(x, 0)
__device__ __forceinline__ float splus(float x) { return fmaxf(x, 0.0f) + log1pf(expf(-fabsf(x))); }

// fp16 pair dot with fp32 accumulate: v_dot2_f32_f16
__device__ __forceinline__ float dot2(h2 a, h2 b, float c) {
#if __has_builtin(__builtin_amdgcn_fdot2)
  return __builtin_amdgcn_fdot2(a, b, c, false);
#else
  c += (float)a.x * (float)b.x;
  c += (float)a.y * (float)b.y;
  return c;
#endif
}

// within-wave LDS ordering fence (no workgroup barrier)
#define LDSFENCE() do { asm volatile("s_waitcnt lgkmcnt(0)" ::: "memory"); \
                        __builtin_amdgcn_sched_barrier(0); } while (0)

#define BC(f) __builtin_bit_cast(h2, f)

// one float4 of packed fp16 weights (8 elems) x 8 fp16 activations, 2 batches
#define DOTF4(W, fa, fb)                                   \
  a0 = dot2(BC((W).x), BC((fa).x), a0);                    \
  a1 = dot2(BC((W).x), BC((fb).x), a1);                    \
  a2 = dot2(BC((W).y), BC((fa).y), a2);                    \
  a3 = dot2(BC((W).y), BC((fb).y), a3);                    \
  a0 = dot2(BC((W).z), BC((fa).z), a0);                    \
  a1 = dot2(BC((W).z), BC((fb).z), a1);                    \
  a2 = dot2(BC((W).w), BC((fa).w), a2);                    \
  a3 = dot2(BC((W).w), BC((fb).w), a3);

#define LSTEP(W, i, Pa, Pb) { float4 fa = (Pa)[i], fb = (Pb)[i]; DOTF4(W, fa, fb) }

__device__ __forceinline__ float4 pack8(const float* p) {
  h2 v0, v1, v2, v3;
  v0.x=(h1)p[0]; v0.y=(h1)p[1]; v1.x=(h1)p[2]; v1.y=(h1)p[3];
  v2.x=(h1)p[4]; v2.y=(h1)p[5]; v3.x=(h1)p[6]; v3.y=(h1)p[7];
  float4 r;
  r.x=__builtin_bit_cast(float,v0); r.y=__builtin_bit_cast(float,v1);
  r.z=__builtin_bit_cast(float,v2); r.w=__builtin_bit_cast(float,v3);
  return r;
}
__device__ __forceinline__ float4 pack6z(const float* p) {
  h2 v0, v1, v2, v3;
  v0.x=(h1)p[0]; v0.y=(h1)p[1]; v1.x=(h1)p[2]; v1.y=(h1)p[3];
  v2.x=(h1)p[4]; v2.y=(h1)p[5]; v3.x=(h1)0.f;  v3.y=(h1)0.f;
  float4 r;
  r.x=__builtin_bit_cast(float,v0); r.y=__builtin_bit_cast(float,v1);
  r.z=__builtin_bit_cast(float,v2); r.w=__builtin_bit_cast(float,v3);
  return r;
}

__global__ __launch_bounds__(BLK)
void dnc_halfrow_kernel(
    const float* __restrict__ x,
    const float* __restrict__ Wih0, const float* __restrict__ Whh0, const float* __restrict__ b0,
    const float* __restrict__ Wih1, const float* __restrict__ Whh1, const float* __restrict__ b1,
    const float* __restrict__ Wif,  const float* __restrict__ bif,
    const float* __restrict__ Wout, const float* __restrict__ bout,
    float* __restrict__ out)
{
  // ---- LDS ----
  __shared__ __align__(16) float4 s_wih0T[4][512];   // [chunk][row]: Wih0 row-elems 8c..8c+7 (pad>=30), lane-contiguous
  __shared__ __align__(16) float4 s_wifT[16][90];    // [chunk][row]: Wif, lane-contiguous, row-padded
  __shared__ __align__(16) float s_gp[2][GB][512];   // [half][batch][row] gate partials
  __shared__ __align__(16) float s_fp[NIF][18];      // interface partials [row][2c+b], padded
  __shared__ __align__(16) float s_b0[512], s_b1[512];
  __shared__ float s_bif[NIF];
  __shared__ __align__(16) h1   s_inph[GB][32];      // [x(10), rv(20), pad(2)] fp16
  __shared__ __align__(16) h1   s_h0h[GB][HID];
  __shared__ __align__(16) h1   s_h1h[GB][HID];
  __shared__ __align__(16) h1   s_ctrlh[GB][HID];
  __shared__ __align__(16) float s_ctrl[GB][HID];    // fp32 for epilogue
  __shared__ __align__(16) float s_mem[GB][NC][CW];
  __shared__ float s_rk[GB][CW], s_wk[GB][CW], s_er[GB][CW], s_wv[GB][CW];
  __shared__ float s_mraw[GB][3];
  __shared__ float s_sc[GB][8];     // 0:rs 1:ws 2:fg 3:ga 4:gw 5:m0 6:m1 7:m2
  __shared__ float s_usage[GB][NC], s_u[GB][NC];
  __shared__ float s_prec[GB][NC], s_prec2[GB][NC];
  __shared__ float s_link[GB][NC][NC];
  __shared__ float s_rw[GB][NC], s_ww[GB][NC];
  __shared__ float s_rv[GB][CW];
  __shared__ float s_cw[GB][NC], s_cr[GB][NC], s_fwd[GB][NC], s_bwd[GB][NC];

  const int tid = threadIdx.x;
  const int bg  = blockIdx.x * GB;
  const int r   = tid & 511;        // gate row owned by this thread
  const int hh  = tid >> 9;         // half (0: k 0..63, 1: k 64..127) — wave-uniform

  // ---- named-SSA register weights: HALF-rows of the 3 recurrent matrices = 96 VGPRs ----
  float4 B0,B1,B2,B3,B4,B5,B6,B7;   // Whh0[r][hh*64 .. hh*64+63]
  float4 C0,C1,C2,C3,C4,C5,C6,C7;   // Wih1[r][...]
  float4 D0,D1,D2,D3,D4,D5,D6,D7;   // Whh1[r][...]
  {
    const float* q0 = Whh0 + (size_t)r*HID + hh*64;
    B0=pack8(q0);    B1=pack8(q0+8);  B2=pack8(q0+16); B3=pack8(q0+24);
    B4=pack8(q0+32); B5=pack8(q0+40); B6=pack8(q0+48); B7=pack8(q0+56);
    const float* q1 = Wih1 + (size_t)r*HID + hh*64;
    C0=pack8(q1);    C1=pack8(q1+8);  C2=pack8(q1+16); C3=pack8(q1+24);
    C4=pack8(q1+32); C5=pack8(q1+40); C6=pack8(q1+48); C7=pack8(q1+56);
    const float* q2 = Whh1 + (size_t)r*HID + hh*64;
    D0=pack8(q2);    D1=pack8(q2+8);  D2=pack8(q2+16); D3=pack8(q2+24);
    D4=pack8(q2+32); D5=pack8(q2+40); D6=pack8(q2+48); D7=pack8(q2+56);
  }

  // ---- LDS weight staging (transposed, lane-contiguous) ----
  for (int idx = tid; idx < 4*512; idx += BLK) {
    int c = idx >> 9, rr = idx & 511;
    const float* p = Wih0 + (size_t)rr*(NIN+CW) + 8*c;
    s_wih0T[c][rr] = (c < 3) ? pack8(p) : pack6z(p);   // elems 24..29 + pad
  }
  for (int idx = tid; idx < 16*NIF; idx += BLK) {
    int j = idx / NIF, q = idx - j*NIF;
    s_wifT[j][q] = pack8(Wif + (size_t)q*HID + 8*j);
  }
  if (tid < 512) { s_b0[tid] = b0[tid]; s_b1[tid] = b1[tid]; }
  if (tid < NIF) s_bif[tid] = bif[tid];

  // ---- zero-init state ----
  if (tid < GB*HID) { int b=tid>>7, j=tid&127;
    s_h0h[b][j]=(h1)0.f; s_h1h[b][j]=(h1)0.f; s_ctrlh[b][j]=(h1)0.f; s_ctrl[b][j]=0.f; }
  for (int i = tid; i < GB*NC*CW; i += BLK) { int b=i/(NC*CW), e=i%(NC*CW);
    s_mem[b][e/CW][e%CW]=0.f; }
  for (int i = tid; i < GB*NC*NC; i += BLK) { int b=i/(NC*NC), e=i%(NC*NC);
    s_link[b][e/NC][e%NC]=0.f; }
  if (tid < GB*NC) { int b=tid/NC, n=tid%NC;
    s_usage[b][n]=0.f; s_prec[b][n]=0.f; s_rw[b][n]=0.f; s_ww[b][n]=0.f; }
  if (tid < GB*CW) { int b=tid/CW, c=tid%CW; s_rv[b][c]=0.f; }
  if (tid < GB*32) { int b=tid>>5, i=tid&31;
    float v = 0.f;
    if (i < NIN) v = x[((size_t)(bg+b)*NT + 0)*NIN + i];
    s_inph[b][i] = (h1)v;
  }
  float c0r = 0.f, c1r = 0.f;   // LSTM cell states (threads 0..255: b=tid>>7, j=tid&127)
  __syncthreads();

  for (int t = 0; t < NT; ++t) {
    // ---- B: half-row partials of gates0 = [x,rv]@Wih0^T + h0_old@Whh0^T ----
    {
      float a0=0.f, a1=0.f, a2=0.f, a3=0.f;
      float4 w0a = s_wih0T[2*hh  ][r];
      float4 w0b = s_wih0T[2*hh+1][r];
      const float4* Ia = (const float4*)s_inph[0] + 2*hh;
      const float4* Ib = (const float4*)s_inph[1] + 2*hh;
      LSTEP(w0a, 0, Ia, Ib)
      LSTEP(w0b, 1, Ia, Ib)
      const float4* Ha = (const float4*)s_h0h[0] + 8*hh;
      const float4* Hb = (const float4*)s_h0h[1] + 8*hh;
      LSTEP(B0,0,Ha,Hb) LSTEP(B1,1,Ha,Hb) LSTEP(B2,2,Ha,Hb) LSTEP(B3,3,Ha,Hb)
      LSTEP(B4,4,Ha,Hb) LSTEP(B5,5,Ha,Hb) LSTEP(B6,6,Ha,Hb) LSTEP(B7,7,Ha,Hb)
      s_gp[hh][0][r] = a0+a2; s_gp[hh][1][r] = a1+a3;
    }
    __syncthreads();

    // ---- C: LSTM0 nonlinearity (combine partials + bias) ----
    if (tid < GB*HID) {
      int b = tid>>7, j = tid&127;
      float gi = s_gp[0][b][j]       + s_gp[1][b][j]       + s_b0[j];
      float gf = s_gp[0][b][128+j]   + s_gp[1][b][128+j]   + s_b0[128+j];
      float gg = s_gp[0][b][256+j]   + s_gp[1][b][256+j]   + s_b0[256+j];
      float go = s_gp[0][b][384+j]   + s_gp[1][b][384+j]   + s_b0[384+j];
      float c = sigf(gf)*c0r + sigf(gi)*tanhf(gg);
      c0r = c;
      float h = sigf(go)*tanhf(c);
      s_h0h[b][j] = (h1)h;
    }
    __syncthreads();

    // ---- D: half-row partials of gates1 = h0_new@Wih1^T + h1_old@Whh1^T ----
    {
      float a0=0.f, a1=0.f, a2=0.f, a3=0.f;
      const float4* Ha = (const float4*)s_h0h[0] + 8*hh;
      const float4* Hb = (const float4*)s_h0h[1] + 8*hh;
      LSTEP(C0,0,Ha,Hb) LSTEP(C1,1,Ha,Hb) LSTEP(C2,2,Ha,Hb) LSTEP(C3,3,Ha,Hb)
      LSTEP(C4,4,Ha,Hb) LSTEP(C5,5,Ha,Hb) LSTEP(C6,6,Ha,Hb) LSTEP(C7,7,Ha,Hb)
      const float4* Ga = (const float4*)s_h1h[0] + 8*hh;
      const float4* Gb = (const float4*)s_h1h[1] + 8*hh;
      LSTEP(D0,0,Ga,Gb) LSTEP(D1,1,Ga,Gb) LSTEP(D2,2,Ga,Gb) LSTEP(D3,3,Ga,Gb)
      LSTEP(D4,4,Ga,Gb) LSTEP(D5,5,Ga,Gb) LSTEP(D6,6,Ga,Gb) LSTEP(D7,7,Ga,Gb)
      s_gp[hh][0][r] = a0+a2; s_gp[hh][1][r] = a1+a3;
    }
    __syncthreads();

    // ---- E: LSTM1 nonlinearity + ctrl clip ----
    if (tid < GB*HID) {
      int b = tid>>7, j = tid&127;
      float gi = s_gp[0][b][j]       + s_gp[1][b][j]       + s_b1[j];
      float gf = s_gp[0][b][128+j]   + s_gp[1][b][128+j]   + s_b1[128+j];
      float gg = s_gp[0][b][256+j]   + s_gp[1][b][256+j]   + s_b1[256+j];
      float go = s_gp[0][b][384+j]   + s_gp[1][b][384+j]   + s_b1[384+j];
      float c = sigf(gf)*c1r + sigf(gi)*tanhf(gg);
      c1r = c;
      float h = sigf(go)*tanhf(c);
      float ctl = fminf(fmaxf(h, -20.f), 20.f);
      s_h1h[b][j] = (h1)h;
      s_ctrl[b][j] = ctl;
      s_ctrlh[b][j] = (h1)ctl;
    }
    __syncthreads();

    // ---- F: interface partials, 8 threads per row (LDS weights, lane-contiguous) ----
    if (tid < 8*NIF) {
      int q = tid >> 3, c = tid & 7;
      float a0=0.f, a1=0.f, a2=0.f, a3=0.f;
      float4 wa = s_wifT[2*c  ][q];
      float4 wb = s_wifT[2*c+1][q];
      const float4* Ca = (const float4*)s_ctrlh[0] + 2*c;
      const float4* Cb = (const float4*)s_ctrlh[1] + 2*c;
      LSTEP(wa, 0, Ca, Cb)
      LSTEP(wb, 1, Ca, Cb)
      s_fp[q][2*c  ] = a0+a2;
      s_fp[q][2*c+1] = a1+a3;
    }
    __syncthreads();

    // ---- W0: F-combine + all DNC memory ops, wave 0 only, LDS fences not barriers ----
    if (tid < 64) {
      const int lane = tid;
      // prefetch next x early (latency hidden under combine/H..L)
      float xv = 0.f;
      if (lane >= GB*CW && lane < GB*CW + GB*NIN && (t+1) < NT) {
        int q = lane - GB*CW, b = q/NIN, i = q%NIN;
        xv = x[((size_t)(bg+b)*NT + (t+1))*NIN + i];
      }

      // F-combine: xi = bif + sum of 8 partials, fused transforms
      #pragma unroll
      for (int e = lane; e < 2*NIF; e += 64) {
        int b = e & 1, q = e >> 1;
        float a = s_bif[q];
        #pragma unroll
        for (int c = 0; c < 8; ++c) a += s_fp[q][2*c+b];
        if      (q < 20)  s_rk[b][q]    = tanhf(a);
        else if (q == 20) s_sc[b][0]    = splus(a);
        else if (q < 41)  s_wk[b][q-21] = tanhf(a);
        else if (q == 41) s_sc[b][1]    = splus(a);
        else if (q < 62)  s_er[b][q-42] = sigf(a);
        else if (q < 82)  s_wv[b][q-62] = tanhf(a);
        else if (q == 82) s_sc[b][2]    = sigf(a);
        else if (q == 83) s_sc[b][3]    = sigf(a);
        else if (q == 84) s_sc[b][4]    = sigf(a);
        else              s_mraw[b][q-85] = a;
      }
      LDSFENCE();

      // H: usage/psi + write-content sims + modes softmax
      if (lane < GB*NC) {
        int b = lane/NC, n = lane%NC;
        float fg = s_sc[b][2];
        float psi = 1.f - fg * s_rw[b][n];
        float u = s_usage[b][n], w = s_ww[b][n];
        u = (u + w - u*w) * psi;
        s_usage[b][n] = u;
        s_u[b][n] = 1e-6f + (1.0f - 1e-6f) * u;
        float dot=0.f, mn=0.f, kn=0.f;
        #pragma unroll
        for (int c = 0; c < CW; ++c) {
          float m = s_mem[b][n][c], k = s_wk[b][c];
          dot += k*m; mn += m*m; kn += k*k;
        }
        s_cw[b][n] = dot / (sqrtf(kn)*sqrtf(mn) + 1e-6f) * s_sc[b][1];
      } else if (lane < GB*NC + GB) {
        int b = lane - GB*NC;
        float m0=s_mraw[b][0], m1=s_mraw[b][1], m2=s_mraw[b][2];
        float mm = fmaxf(m0, fmaxf(m1, m2));
        float e0=expf(m0-mm), e1=expf(m1-mm), e2=expf(m2-mm);
        float es = e0+e1+e2;
        s_sc[b][5]=e0/es; s_sc[b][6]=e1/es; s_sc[b][7]=e2/es;
      }
      LDSFENCE();

      // I: cw softmax + rank-based allocation + new ww
      if (lane < GB*NC) {
        int b = lane/NC, n = lane%NC;
        float mx = -1e30f;
        #pragma unroll
        for (int m = 0; m < NC; ++m) mx = fmaxf(mx, s_cw[b][m]);
        float sm = 0.f;
        #pragma unroll
        for (int m = 0; m < NC; ++m) sm += expf(s_cw[b][m]-mx);
        float cwv = expf(s_cw[b][n]-mx) / sm;
        float un = s_u[b][n];
        float excl = 1.f;
        #pragma unroll
        for (int m = 0; m < NC; ++m) {
          float um = s_u[b][m];
          bool before = (um < un) || (um == un && m < n);
          excl *= before ? um : 1.f;
        }
        float alloc = (1.f - un) * excl;
        float ga = s_sc[b][3], gw = s_sc[b][4];
        s_ww[b][n] = gw * (ga*alloc + (1.f-ga)*cwv);
      }
      LDSFENCE();

      // J: memory write + link update (old prec) + prec2
      #pragma unroll
      for (int e = lane; e < GB*NC*CW; e += 64) {
        int b = e/(NC*CW), rr = (e%(NC*CW))/CW, c = e%CW;
        float w = s_ww[b][rr];
        s_mem[b][rr][c] = s_mem[b][rr][c] * (1.f - w*s_er[b][c]) + w*s_wv[b][c];
      }
      #pragma unroll
      for (int e = lane; e < GB*NC*NC; e += 64) {
        int b = e/(NC*NC), i = (e%(NC*NC))/NC, j = e%NC;
        float wi = s_ww[b][i], wj = s_ww[b][j];
        float l = (1.f - wi - wj)*s_link[b][i][j] + wi*s_prec[b][j];
        s_link[b][i][j] = (i==j) ? 0.f : l;
      }
      if (lane < GB*NC) {
        int b = lane/NC, n = lane%NC;
        float sw2 = 0.f;
        #pragma unroll
        for (int m = 0; m < NC; ++m) sw2 += s_ww[b][m];
        s_prec2[b][n] = (1.f - sw2)*s_prec[b][n] + s_ww[b][n];
      }
      LDSFENCE();

      // K: commit prec, fwd/bwd on new link, read-content sims on new mem
      if (lane < GB*NC) {
        int b = lane/NC, m = lane%NC;
        s_prec[b][m] = s_prec2[b][m];
        float a = 0.f;
        #pragma unroll
        for (int n = 0; n < NC; ++n) a += s_rw[b][n]*s_link[b][m][n];
        s_fwd[b][m] = a;
      } else if (lane < 2*GB*NC) {
        int q = lane - GB*NC, b = q/NC, m = q%NC;
        float a = 0.f;
        #pragma unroll
        for (int n = 0; n < NC; ++n) a += s_rw[b][n]*s_link[b][n][m];
        s_bwd[b][m] = a;
      } else if (lane < 3*GB*NC) {
        int q = lane - 2*GB*NC, b = q/NC, n = q%NC;
        float dot=0.f, mn=0.f, kn=0.f;
        #pragma unroll
        for (int c = 0; c < CW; ++c) {
          float m = s_mem[b][n][c], k = s_rk[b][c];
          dot += k*m; mn += m*m; kn += k*k;
        }
        s_cr[b][n] = dot/(sqrtf(kn)*sqrtf(mn)+1e-6f) * s_sc[b][0];
      }
      LDSFENCE();

      // L: cr softmax + new read weights
      if (lane < GB*NC) {
        int b = lane/NC, n = lane%NC;
        float mx = -1e30f;
        #pragma unroll
        for (int m = 0; m < NC; ++m) mx = fmaxf(mx, s_cr[b][m]);
        float sm = 0.f;
        #pragma unroll
        for (int m = 0; m < NC; ++m) sm += expf(s_cr[b][m]-mx);
        float cr = expf(s_cr[b][n]-mx)/sm;
        s_rw[b][n] = s_sc[b][5]*s_bwd[b][n] + s_sc[b][6]*cr + s_sc[b][7]*s_fwd[b][n];
      }
      LDSFENCE();

      // M: read vectors + pack next-step input (x part from prefetch)
      if (lane < GB*CW) {
        int b = lane/CW, c = lane%CW;
        float a = 0.f;
        #pragma unroll
        for (int n = 0; n < NC; ++n) a += s_rw[b][n]*s_mem[b][n][c];
        s_rv[b][c] = a;
        s_inph[b][NIN + c] = (h1)a;
      } else if (lane < GB*CW + GB*NIN && (t+1) < NT) {
        int q = lane - GB*CW, b = q/NIN, i = q%NIN;
        s_inph[b][i] = (h1)xv;
      }
    }
    __syncthreads();
  }

  // ---- epilogue: y_T = [ctrl, rv] @ Wout^T + bout ----
  if (tid < GB*NOUT) {
    int b = tid/NOUT, o = tid%NOUT;
    float a = bout[o];
    const float* Wr = Wout + o*(HID+CW);
    #pragma unroll 4
    for (int k = 0; k < HID; ++k) a += Wr[k]*s_ctrl[b][k];
    #pragma unroll
    for (int c = 0; c < CW; ++c) a += Wr[HID+c]*s_rv[b][c];
    out[(size_t)(bg+b)*NOUT + o] = a;
  }
}

extern "C" void kernel_launch(void* const* d_in, const int* in_sizes, int n_in,
                              void* d_out, int out_size, void* d_ws, size_t ws_size,
                              hipStream_t stream) {
  (void)in_sizes; (void)n_in; (void)out_size; (void)d_ws; (void)ws_size;
  const float* x    = (const float*)d_in[0];
  const float* Wih0 = (const float*)d_in[1];
  const float* Whh0 = (const float*)d_in[2];
  const float* b0   = (const float*)d_in[3];
  const float* Wih1 = (const float*)d_in[4];
  const float* Whh1 = (const float*)d_in[5];
  const float* b1   = (const float*)d_in[6];
  const float* Wif  = (const float*)d_in[7];
  const float* bif  = (const float*)d_in[8];
  const float* Wout = (const float*)d_in[9];
  const float* bout = (const float*)d_in[10];
  float* out = (float*)d_out;
  dnc_halfrow_kernel<<<dim3(NB/GB), dim3(BLK), 0, stream>>>(
      x, Wih0, Whh0, b0, Wih1, Whh1, b1, Wif, bif, Wout, bout, out);
}

// Round 6
// 7670.513 us; speedup vs baseline: 1.3165x; 1.3165x over previous
//
#include <hip/hip_runtime.h>
#include <math.h>

#define NT 512        // time steps
#define NB 512        // batch
#define HID 128
#define NIN 10
#define NC 10         // memory cells
#define CW 20         // cell width
#define NIF 88        // interface size
#define NOUT 10
#define GB 2          // batches per workgroup
#define BLK 1024      // 16 waves; LDS>80KB forces 1 block/CU -> 4 waves/EU -> 128-VGPR budget

typedef _Float16 h1;
typedef _Float16 h2 __attribute__((ext_vector_type(2)));

__device__ __forceinline__ float sigf(float x) { return 1.0f / (1.0f + expf(-x)); }
// jax.nn.softplus == logaddexp(x, 0)
__device__ __forceinline__ float splus(float x) { return fmaxf(x, 0.0f) + log1pf(expf(-fabsf(x))); }

// fp16 pair dot with fp32 accumulate: v_dot2_f32_f16
__device__ __forceinline__ float dot2(h2 a, h2 b, float c) {
#if __has_builtin(__builtin_amdgcn_fdot2)
  return __builtin_amdgcn_fdot2(a, b, c, false);
#else
  c += (float)a.x * (float)b.x;
  c += (float)a.y * (float)b.y;
  return c;
#endif
}

// within-wave LDS ordering fence (no workgroup barrier)
#define LDSFENCE() do { asm volatile("s_waitcnt lgkmcnt(0)" ::: "memory"); \
                        __builtin_amdgcn_sched_barrier(0); } while (0)

#define BC(f) __builtin_bit_cast(h2, f)

// one float4 of packed fp16 weights (8 elems) x 8 fp16 activations, 2 batches
#define DOTF4(W, fa, fb)                                   \
  a0 = dot2(BC((W).x), BC((fa).x), a0);                    \
  a1 = dot2(BC((W).x), BC((fb).x), a1);                    \
  a2 = dot2(BC((W).y), BC((fa).y), a2);                    \
  a3 = dot2(BC((W).y), BC((fb).y), a3);                    \
  a0 = dot2(BC((W).z), BC((fa).z), a0);                    \
  a1 = dot2(BC((W).z), BC((fb).z), a1);                    \
  a2 = dot2(BC((W).w), BC((fa).w), a2);                    \
  a3 = dot2(BC((W).w), BC((fb).w), a3);

#define LSTEP(W, i, Pa, Pb) { float4 fa = (Pa)[i], fb = (Pb)[i]; DOTF4(W, fa, fb) }

__device__ __forceinline__ float4 pack8(const float* p) {
  h2 v0, v1, v2, v3;
  v0.x=(h1)p[0]; v0.y=(h1)p[1]; v1.x=(h1)p[2]; v1.y=(h1)p[3];
  v2.x=(h1)p[4]; v2.y=(h1)p[5]; v3.x=(h1)p[6]; v3.y=(h1)p[7];
  float4 r;
  r.x=__builtin_bit_cast(float,v0); r.y=__builtin_bit_cast(float,v1);
  r.z=__builtin_bit_cast(float,v2); r.w=__builtin_bit_cast(float,v3);
  return r;
}
__device__ __forceinline__ float4 pack6z(const float* p) {
  h2 v0, v1, v2, v3;
  v0.x=(h1)p[0]; v0.y=(h1)p[1]; v1.x=(h1)p[2]; v1.y=(h1)p[3];
  v2.x=(h1)p[4]; v2.y=(h1)p[5]; v3.x=(h1)0.f;  v3.y=(h1)0.f;
  float4 r;
  r.x=__builtin_bit_cast(float,v0); r.y=__builtin_bit_cast(float,v1);
  r.z=__builtin_bit_cast(float,v2); r.w=__builtin_bit_cast(float,v3);
  return r;
}

__global__ __launch_bounds__(BLK) __attribute__((amdgpu_waves_per_eu(4, 4)))
void dnc_halfrow128_kernel(
    const float* __restrict__ x,
    const float* __restrict__ Wih0, const float* __restrict__ Whh0, const float* __restrict__ b0,
    const float* __restrict__ Wih1, const float* __restrict__ Whh1, const float* __restrict__ b1,
    const float* __restrict__ Wif,  const float* __restrict__ bif,
    const float* __restrict__ Wout, const float* __restrict__ bout,
    float* __restrict__ out)
{
  // ---- LDS (~113 KB total: must stay > 80 KB so only 1 block/CU fits) ----
  __shared__ __align__(16) float4 s_wih0T[4][512];      // [chunk][row] Wih0 elems 8c..8c+7 (chunk3 zero-padded)
  __shared__ __align__(16) float4 s_whh1t[2][2][512];   // [half][c][row]: Whh1 k = h*64+48+8c .. +7
  __shared__ __align__(16) float4 s_wifT[16*89];        // [chunk*89+row] Wif, stride-89 padded
  __shared__ __align__(16) float s_gp[2][GB][512];      // [half][batch][row] gate partials
  __shared__ __align__(16) float s_fp[NIF][18];         // interface partials [row][2c+b]
  __shared__ __align__(16) float s_b0[512], s_b1[512];
  __shared__ float s_bif[NIF];
  __shared__ __align__(16) h1   s_inph[GB][32];         // [x(10), rv(20), pad(2)] fp16
  __shared__ __align__(16) h1   s_h0h[GB][HID];
  __shared__ __align__(16) h1   s_h1h[GB][HID];
  __shared__ __align__(16) h1   s_ctrlh[GB][HID];
  __shared__ __align__(16) float s_ctrl[GB][HID];       // fp32 for epilogue
  __shared__ __align__(16) float s_mem[GB][NC][CW];
  __shared__ float s_rk[GB][CW], s_wk[GB][CW], s_er[GB][CW], s_wv[GB][CW];
  __shared__ float s_mraw[GB][3];
  __shared__ float s_sc[GB][8];     // 0:rs 1:ws 2:fg 3:ga 4:gw 5:m0 6:m1 7:m2
  __shared__ float s_usage[GB][NC], s_u[GB][NC];
  __shared__ float s_prec[GB][NC], s_prec2[GB][NC];
  __shared__ float s_link[GB][NC][NC];
  __shared__ float s_rw[GB][NC], s_ww[GB][NC];
  __shared__ float s_rv[GB][CW];
  __shared__ float s_cw[GB][NC], s_cr[GB][NC], s_fwd[GB][NC], s_bwd[GB][NC];

  const int tid = threadIdx.x;
  const int bg  = blockIdx.x * GB;
  const int r   = tid & 511;        // gate row owned by this thread
  const int hh  = tid >> 9;         // half (0: k 0..63, 1: k 64..127) — wave-uniform

  // ---- named-SSA register weights: 22 float4 = 88 VGPRs ----
  float4 B0,B1,B2,B3,B4,B5,B6,B7;   // Whh0[r][hh*64 .. +63]
  float4 C0,C1,C2,C3,C4,C5,C6,C7;   // Wih1[r][hh*64 .. +63]
  float4 D0,D1,D2,D3,D4,D5;         // Whh1[r][hh*64 .. +47] (last 16 in LDS)
  {
    const float* q0 = Whh0 + (size_t)r*HID + hh*64;
    B0=pack8(q0);    B1=pack8(q0+8);  B2=pack8(q0+16); B3=pack8(q0+24);
    B4=pack8(q0+32); B5=pack8(q0+40); B6=pack8(q0+48); B7=pack8(q0+56);
    const float* q1 = Wih1 + (size_t)r*HID + hh*64;
    C0=pack8(q1);    C1=pack8(q1+8);  C2=pack8(q1+16); C3=pack8(q1+24);
    C4=pack8(q1+32); C5=pack8(q1+40); C6=pack8(q1+48); C7=pack8(q1+56);
    const float* q2 = Whh1 + (size_t)r*HID + hh*64;
    D0=pack8(q2);    D1=pack8(q2+8);  D2=pack8(q2+16); D3=pack8(q2+24);
    D4=pack8(q2+32); D5=pack8(q2+40);
  }

  // ---- LDS weight staging (transposed, lane-contiguous) ----
  for (int idx = tid; idx < 4*512; idx += BLK) {
    int c = idx >> 9, rr = idx & 511;
    const float* p = Wih0 + (size_t)rr*(NIN+CW) + 8*c;
    s_wih0T[c][rr] = (c < 3) ? pack8(p) : pack6z(p);   // elems 24..29 + pad
  }
  for (int idx = tid; idx < 2*2*512; idx += BLK) {
    int h = idx >> 10, c = (idx >> 9) & 1, rr = idx & 511;
    s_whh1t[h][c][rr] = pack8(Whh1 + (size_t)rr*HID + h*64 + 48 + 8*c);
  }
  for (int idx = tid; idx < 16*NIF; idx += BLK) {
    int j = idx / NIF, q = idx - j*NIF;
    s_wifT[j*89 + q] = pack8(Wif + (size_t)q*HID + 8*j);
  }
  if (tid < 512) { s_b0[tid] = b0[tid]; s_b1[tid] = b1[tid]; }
  if (tid < NIF) s_bif[tid] = bif[tid];

  // ---- zero-init state ----
  if (tid < GB*HID) { int b=tid>>7, j=tid&127;
    s_h0h[b][j]=(h1)0.f; s_h1h[b][j]=(h1)0.f; s_ctrlh[b][j]=(h1)0.f; s_ctrl[b][j]=0.f; }
  for (int i = tid; i < GB*NC*CW; i += BLK) { int b=i/(NC*CW), e=i%(NC*CW);
    s_mem[b][e/CW][e%CW]=0.f; }
  for (int i = tid; i < GB*NC*NC; i += BLK) { int b=i/(NC*NC), e=i%(NC*NC);
    s_link[b][e/NC][e%NC]=0.f; }
  if (tid < GB*NC) { int b=tid/NC, n=tid%NC;
    s_usage[b][n]=0.f; s_prec[b][n]=0.f; s_rw[b][n]=0.f; s_ww[b][n]=0.f; }
  if (tid < GB*CW) { int b=tid/CW, c=tid%CW; s_rv[b][c]=0.f; }
  if (tid < GB*32) { int b=tid>>5, i=tid&31;
    float v = 0.f;
    if (i < NIN) v = x[((size_t)(bg+b)*NT + 0)*NIN + i];
    s_inph[b][i] = (h1)v;
  }
  float c0r = 0.f, c1r = 0.f;   // LSTM cell states (threads 0..255: b=tid>>7, j=tid&127)
  __syncthreads();

  for (int t = 0; t < NT; ++t) {
    // ---- B: half-row partials of gates0 = [x,rv]@Wih0^T + h0_old@Whh0^T ----
    {
      float a0=0.f, a1=0.f, a2=0.f, a3=0.f;
      float4 w0a = s_wih0T[2*hh  ][r];
      float4 w0b = s_wih0T[2*hh+1][r];
      const float4* Ia = (const float4*)s_inph[0] + 2*hh;
      const float4* Ib = (const float4*)s_inph[1] + 2*hh;
      LSTEP(w0a, 0, Ia, Ib)
      LSTEP(w0b, 1, Ia, Ib)
      const float4* Ha = (const float4*)s_h0h[0] + 8*hh;
      const float4* Hb = (const float4*)s_h0h[1] + 8*hh;
      LSTEP(B0,0,Ha,Hb) LSTEP(B1,1,Ha,Hb) LSTEP(B2,2,Ha,Hb) LSTEP(B3,3,Ha,Hb)
      LSTEP(B4,4,Ha,Hb) LSTEP(B5,5,Ha,Hb) LSTEP(B6,6,Ha,Hb) LSTEP(B7,7,Ha,Hb)
      s_gp[hh][0][r] = a0+a2; s_gp[hh][1][r] = a1+a3;
    }
    __syncthreads();

    // ---- C: LSTM0 nonlinearity (combine partials + bias) ----
    if (tid < GB*HID) {
      int b = tid>>7, j = tid&127;
      float gi = s_gp[0][b][j]       + s_gp[1][b][j]       + s_b0[j];
      float gf = s_gp[0][b][128+j]   + s_gp[1][b][128+j]   + s_b0[128+j];
      float gg = s_gp[0][b][256+j]   + s_gp[1][b][256+j]   + s_b0[256+j];
      float go = s_gp[0][b][384+j]   + s_gp[1][b][384+j]   + s_b0[384+j];
      float c = sigf(gf)*c0r + sigf(gi)*tanhf(gg);
      c0r = c;
      float h = sigf(go)*tanhf(c);
      s_h0h[b][j] = (h1)h;
    }
    __syncthreads();

    // ---- D: half-row partials of gates1 = h0_new@Wih1^T + h1_old@Whh1^T ----
    {
      float a0=0.f, a1=0.f, a2=0.f, a3=0.f;
      const float4* Ha = (const float4*)s_h0h[0] + 8*hh;
      const float4* Hb = (const float4*)s_h0h[1] + 8*hh;
      LSTEP(C0,0,Ha,Hb) LSTEP(C1,1,Ha,Hb) LSTEP(C2,2,Ha,Hb) LSTEP(C3,3,Ha,Hb)
      LSTEP(C4,4,Ha,Hb) LSTEP(C5,5,Ha,Hb) LSTEP(C6,6,Ha,Hb) LSTEP(C7,7,Ha,Hb)
      const float4* Ga = (const float4*)s_h1h[0] + 8*hh;
      const float4* Gb = (const float4*)s_h1h[1] + 8*hh;
      LSTEP(D0,0,Ga,Gb) LSTEP(D1,1,Ga,Gb) LSTEP(D2,2,Ga,Gb) LSTEP(D3,3,Ga,Gb)
      LSTEP(D4,4,Ga,Gb) LSTEP(D5,5,Ga,Gb)
      float4 w6 = s_whh1t[hh][0][r];
      float4 w7 = s_whh1t[hh][1][r];
      LSTEP(w6,6,Ga,Gb) LSTEP(w7,7,Ga,Gb)
      s_gp[hh][0][r] = a0+a2; s_gp[hh][1][r] = a1+a3;
    }
    __syncthreads();

    // ---- E: LSTM1 nonlinearity + ctrl clip ----
    if (tid < GB*HID) {
      int b = tid>>7, j = tid&127;
      float gi = s_gp[0][b][j]       + s_gp[1][b][j]       + s_b1[j];
      float gf = s_gp[0][b][128+j]   + s_gp[1][b][128+j]   + s_b1[128+j];
      float gg = s_gp[0][b][256+j]   + s_gp[1][b][256+j]   + s_b1[256+j];
      float go = s_gp[0][b][384+j]   + s_gp[1][b][384+j]   + s_b1[384+j];
      float c = sigf(gf)*c1r + sigf(gi)*tanhf(gg);
      c1r = c;
      float h = sigf(go)*tanhf(c);
      float ctl = fminf(fmaxf(h, -20.f), 20.f);
      s_h1h[b][j] = (h1)h;
      s_ctrl[b][j] = ctl;
      s_ctrlh[b][j] = (h1)ctl;
    }
    __syncthreads();

    // ---- F: interface partials, 8 threads per row (LDS weights, lane-contiguous) ----
    if (tid < 8*NIF) {
      int q = tid >> 3, c = tid & 7;
      float a0=0.f, a1=0.f, a2=0.f, a3=0.f;
      float4 wa = s_wifT[(2*c  )*89 + q];
      float4 wb = s_wifT[(2*c+1)*89 + q];
      const float4* Ca = (const float4*)s_ctrlh[0] + 2*c;
      const float4* Cb = (const float4*)s_ctrlh[1] + 2*c;
      LSTEP(wa, 0, Ca, Cb)
      LSTEP(wb, 1, Ca, Cb)
      s_fp[q][2*c  ] = a0+a2;
      s_fp[q][2*c+1] = a1+a3;
    }
    __syncthreads();

    // ---- W0: F-combine + all DNC memory ops, wave 0 only, LDS fences not barriers ----
    if (tid < 64) {
      const int lane = tid;
      // prefetch next x early (latency hidden under combine/H..L)
      float xv = 0.f;
      if (lane >= GB*CW && lane < GB*CW + GB*NIN && (t+1) < NT) {
        int q = lane - GB*CW, b = q/NIN, i = q%NIN;
        xv = x[((size_t)(bg+b)*NT + (t+1))*NIN + i];
      }

      // F-combine: xi = bif + sum of 8 partials, fused transforms
      #pragma unroll
      for (int e = lane; e < 2*NIF; e += 64) {
        int b = e & 1, q = e >> 1;
        float a = s_bif[q];
        #pragma unroll
        for (int c = 0; c < 8; ++c) a += s_fp[q][2*c+b];
        if      (q < 20)  s_rk[b][q]    = tanhf(a);
        else if (q == 20) s_sc[b][0]    = splus(a);
        else if (q < 41)  s_wk[b][q-21] = tanhf(a);
        else if (q == 41) s_sc[b][1]    = splus(a);
        else if (q < 62)  s_er[b][q-42] = sigf(a);
        else if (q < 82)  s_wv[b][q-62] = tanhf(a);
        else if (q == 82) s_sc[b][2]    = sigf(a);
        else if (q == 83) s_sc[b][3]    = sigf(a);
        else if (q == 84) s_sc[b][4]    = sigf(a);
        else              s_mraw[b][q-85] = a;
      }
      LDSFENCE();

      // H: usage/psi + write-content sims + modes softmax
      if (lane < GB*NC) {
        int b = lane/NC, n = lane%NC;
        float fg = s_sc[b][2];
        float psi = 1.f - fg * s_rw[b][n];
        float u = s_usage[b][n], w = s_ww[b][n];
        u = (u + w - u*w) * psi;
        s_usage[b][n] = u;
        s_u[b][n] = 1e-6f + (1.0f - 1e-6f) * u;
        float dot=0.f, mn=0.f, kn=0.f;
        #pragma unroll
        for (int c = 0; c < CW; ++c) {
          float m = s_mem[b][n][c], k = s_wk[b][c];
          dot += k*m; mn += m*m; kn += k*k;
        }
        s_cw[b][n] = dot / (sqrtf(kn)*sqrtf(mn) + 1e-6f) * s_sc[b][1];
      } else if (lane < GB*NC + GB) {
        int b = lane - GB*NC;
        float m0=s_mraw[b][0], m1=s_mraw[b][1], m2=s_mraw[b][2];
        float mm = fmaxf(m0, fmaxf(m1, m2));
        float e0=expf(m0-mm), e1=expf(m1-mm), e2=expf(m2-mm);
        float es = e0+e1+e2;
        s_sc[b][5]=e0/es; s_sc[b][6]=e1/es; s_sc[b][7]=e2/es;
      }
      LDSFENCE();

      // I: cw softmax + rank-based allocation + new ww
      if (lane < GB*NC) {
        int b = lane/NC, n = lane%NC;
        float mx = -1e30f;
        #pragma unroll
        for (int m = 0; m < NC; ++m) mx = fmaxf(mx, s_cw[b][m]);
        float sm = 0.f;
        #pragma unroll
        for (int m = 0; m < NC; ++m) sm += expf(s_cw[b][m]-mx);
        float cwv = expf(s_cw[b][n]-mx) / sm;
        float un = s_u[b][n];
        float excl = 1.f;
        #pragma unroll
        for (int m = 0; m < NC; ++m) {
          float um = s_u[b][m];
          bool before = (um < un) || (um == un && m < n);
          excl *= before ? um : 1.f;
        }
        float alloc = (1.f - un) * excl;
        float ga = s_sc[b][3], gw = s_sc[b][4];
        s_ww[b][n] = gw * (ga*alloc + (1.f-ga)*cwv);
      }
      LDSFENCE();

      // J: memory write + link update (old prec) + prec2
      #pragma unroll
      for (int e = lane; e < GB*NC*CW; e += 64) {
        int b = e/(NC*CW), rr = (e%(NC*CW))/CW, c = e%CW;
        float w = s_ww[b][rr];
        s_mem[b][rr][c] = s_mem[b][rr][c] * (1.f - w*s_er[b][c]) + w*s_wv[b][c];
      }
      #pragma unroll
      for (int e = lane; e < GB*NC*NC; e += 64) {
        int b = e/(NC*NC), i = (e%(NC*NC))/NC, j = e%NC;
        float wi = s_ww[b][i], wj = s_ww[b][j];
        float l = (1.f - wi - wj)*s_link[b][i][j] + wi*s_prec[b][j];
        s_link[b][i][j] = (i==j) ? 0.f : l;
      }
      if (lane < GB*NC) {
        int b = lane/NC, n = lane%NC;
        float sw2 = 0.f;
        #pragma unroll
        for (int m = 0; m < NC; ++m) sw2 += s_ww[b][m];
        s_prec2[b][n] = (1.f - sw2)*s_prec[b][n] + s_ww[b][n];
      }
      LDSFENCE();

      // K: commit prec, fwd/bwd on new link, read-content sims on new mem
      if (lane < GB*NC) {
        int b = lane/NC, m = lane%NC;
        s_prec[b][m] = s_prec2[b][m];
        float a = 0.f;
        #pragma unroll
        for (int n = 0; n < NC; ++n) a += s_rw[b][n]*s_link[b][m][n];
        s_fwd[b][m] = a;
      } else if (lane < 2*GB*NC) {
        int q = lane - GB*NC, b = q/NC, m = q%NC;
        float a = 0.f;
        #pragma unroll
        for (int n = 0; n < NC; ++n) a += s_rw[b][n]*s_link[b][n][m];
        s_bwd[b][m] = a;
      } else if (lane < 3*GB*NC) {
        int q = lane - 2*GB*NC, b = q/NC, n = q%NC;
        float dot=0.f, mn=0.f, kn=0.f;
        #pragma unroll
        for (int c = 0; c < CW; ++c) {
          float m = s_mem[b][n][c], k = s_rk[b][c];
          dot += k*m; mn += m*m; kn += k*k;
        }
        s_cr[b][n] = dot/(sqrtf(kn)*sqrtf(mn)+1e-6f) * s_sc[b][0];
      }
      LDSFENCE();

      // L: cr softmax + new read weights
      if (lane < GB*NC) {
        int b = lane/NC, n = lane%NC;
        float mx = -1e30f;
        #pragma unroll
        for (int m = 0; m < NC; ++m) mx = fmaxf(mx, s_cr[b][m]);
        float sm = 0.f;
        #pragma unroll
        for (int m = 0; m < NC; ++m) sm += expf(s_cr[b][m]-mx);
        float cr = expf(s_cr[b][n]-mx)/sm;
        s_rw[b][n] = s_sc[b][5]*s_bwd[b][n] + s_sc[b][6]*cr + s_sc[b][7]*s_fwd[b][n];
      }
      LDSFENCE();

      // M: read vectors + pack next-step input (x part from prefetch)
      if (lane < GB*CW) {
        int b = lane/CW, c = lane%CW;
        float a = 0.f;
        #pragma unroll
        for (int n = 0; n < NC; ++n) a += s_rw[b][n]*s_mem[b][n][c];
        s_rv[b][c] = a;
        s_inph[b][NIN + c] = (h1)a;
      } else if (lane < GB*CW + GB*NIN && (t+1) < NT) {
        int q = lane - GB*CW, b = q/NIN, i = q%NIN;
        s_inph[b][i] = (h1)xv;
      }
    }
    __syncthreads();
  }

  // ---- epilogue: y_T = [ctrl, rv] @ Wout^T + bout ----
  if (tid < GB*NOUT) {
    int b = tid/NOUT, o = tid%NOUT;
    float a = bout[o];
    const float* Wr = Wout + o*(HID+CW);
    #pragma unroll 4
    for (int k = 0; k < HID; ++k) a += Wr[k]*s_ctrl[b][k];
    #pragma unroll
    for (int c = 0; c < CW; ++c) a += Wr[HID+c]*s_rv[b][c];
    out[(size_t)(bg+b)*NOUT + o] = a;
  }
}

extern "C" void kernel_launch(void* const* d_in, const int* in_sizes, int n_in,
                              void* d_out, int out_size, void* d_ws, size_t ws_size,
                              hipStream_t stream) {
  (void)in_sizes; (void)n_in; (void)out_size; (void)d_ws; (void)ws_size;
  const float* x    = (const float*)d_in[0];
  const float* Wih0 = (const float*)d_in[1];
  const float* Whh0 = (const float*)d_in[2];
  const float* b0   = (const float*)d_in[3];
  const float* Wih1 = (const float*)d_in[4];
  const float* Whh1 = (const float*)d_in[5];
  const float* b1   = (const float*)d_in[6];
  const float* Wif  = (const float*)d_in[7];
  const float* bif  = (const float*)d_in[8];
  const float* Wout = (const float*)d_in[9];
  const float* bout = (const float*)d_in[10];
  float* out = (float*)d_out;
  dnc_halfrow128_kernel<<<dim3(NB/GB), dim3(BLK), 0, stream>>>(
      x, Wih0, Whh0, b0, Wih1, Whh1, b1, Wif, bif, Wout, bout, out);
}

// Round 7
// 6005.083 us; speedup vs baseline: 1.6816x; 1.2773x over previous
//
#include <hip/hip_runtime.h>
#include <math.h>

#define NT 512        // time steps
#define NB 512        // batch
#define HID 128
#define NIN 10
#define NC 10         // memory cells
#define CW 20         // cell width
#define NIF 88        // interface size
#define NOUT 10
#define GB 2          // batches per workgroup
#define BLK 512       // 8 waves; empirical alloc law grants 128 VGPR at this size

typedef _Float16 h1;
typedef _Float16 h2 __attribute__((ext_vector_type(2)));

__device__ __forceinline__ float sigf(float x) { return 1.0f / (1.0f + expf(-x)); }
// jax.nn.softplus == logaddexp(x, 0)
__device__ __forceinline__ float splus(float x) { return fmaxf(x, 0.0f) + log1pf(expf(-fabsf(x))); }

// fp16 pair dot with fp32 accumulate: v_dot2_f32_f16
__device__ __forceinline__ float dot2(h2 a, h2 b, float c) {
#if __has_builtin(__builtin_amdgcn_fdot2)
  return __builtin_amdgcn_fdot2(a, b, c, false);
#else
  c += (float)a.x * (float)b.x;
  c += (float)a.y * (float)b.y;
  return c;
#endif
}

// within-wave LDS ordering fence (no workgroup barrier)
#define LDSFENCE() do { asm volatile("s_waitcnt lgkmcnt(0)" ::: "memory"); \
                        __builtin_amdgcn_sched_barrier(0); } while (0)

#define BC(f) __builtin_bit_cast(h2, f)

// one float4 of packed fp16 weights (8 elems) x 8 fp16 activations, 2 batches
#define DOTF4(W, fa, fb)                                   \
  a0 = dot2(BC((W).x), BC((fa).x), a0);                    \
  a1 = dot2(BC((W).x), BC((fb).x), a1);                    \
  a2 = dot2(BC((W).y), BC((fa).y), a2);                    \
  a3 = dot2(BC((W).y), BC((fb).y), a3);                    \
  a0 = dot2(BC((W).z), BC((fa).z), a0);                    \
  a1 = dot2(BC((W).z), BC((fb).z), a1);                    \
  a2 = dot2(BC((W).w), BC((fa).w), a2);                    \
  a3 = dot2(BC((W).w), BC((fb).w), a3);

#define LSTEP(W, i, Pa, Pb) { float4 fa = (Pa)[i], fb = (Pb)[i]; DOTF4(W, fa, fb) }

__device__ __forceinline__ float4 pack8(const float* p) {
  h2 v0, v1, v2, v3;
  v0.x=(h1)p[0]; v0.y=(h1)p[1]; v1.x=(h1)p[2]; v1.y=(h1)p[3];
  v2.x=(h1)p[4]; v2.y=(h1)p[5]; v3.x=(h1)p[6]; v3.y=(h1)p[7];
  float4 r;
  r.x=__builtin_bit_cast(float,v0); r.y=__builtin_bit_cast(float,v1);
  r.z=__builtin_bit_cast(float,v2); r.w=__builtin_bit_cast(float,v3);
  return r;
}
__device__ __forceinline__ float4 pack6z(const float* p) {
  h2 v0, v1, v2, v3;
  v0.x=(h1)p[0]; v0.y=(h1)p[1]; v1.x=(h1)p[2]; v1.y=(h1)p[3];
  v2.x=(h1)p[4]; v2.y=(h1)p[5]; v3.x=(h1)0.f;  v3.y=(h1)0.f;
  float4 r;
  r.x=__builtin_bit_cast(float,v0); r.y=__builtin_bit_cast(float,v1);
  r.z=__builtin_bit_cast(float,v2); r.w=__builtin_bit_cast(float,v3);
  return r;
}

// ---- convert kernel: pack streamed weights (fp16, transposed [chunk][row]) into d_ws ----
// ws[c*512 + r]        = Whh1[r][8c..8c+7]   for c in 0..15   (128 KB)
// ws[8192 + c2*512 + r]= Wih1[r][112+8c2 .. ] for c2 in 0..1   (16 KB)
__global__ __launch_bounds__(256) void dnc_pack_kernel(
    const float* __restrict__ Wih1, const float* __restrict__ Whh1, float4* __restrict__ ws)
{
  int i = blockIdx.x * 256 + threadIdx.x;   // 0..9215
  if (i < 16*512) {
    int c = i >> 9, rr = i & 511;
    ws[i] = pack8(Whh1 + (size_t)rr*HID + 8*c);
  } else if (i < 18*512) {
    int j = i - 16*512; int c2 = j >> 9, rr = j & 511;
    ws[i] = pack8(Wih1 + (size_t)rr*HID + (14 + c2)*8);
  }
}

__global__ __launch_bounds__(BLK)
void dnc_stream_kernel(
    const float* __restrict__ x,
    const float* __restrict__ Wih0, const float* __restrict__ Whh0, const float* __restrict__ b0,
    const float* __restrict__ Wih1, const float* __restrict__ Whh1, const float* __restrict__ b1,
    const float* __restrict__ Wif,  const float* __restrict__ bif,
    const float* __restrict__ Wout, const float* __restrict__ bout,
    const float4* __restrict__ wsT,
    float* __restrict__ out)
{
  // ---- LDS (~148 KB -> 1 block/CU) ----
  __shared__ __align__(16) float4 s_wih1T[14][512];   // [chunk][row]: Wih1 k=8c..8c+7, lane-contiguous
  __shared__ __align__(16) float4 s_wifT[16*89];      // [chunk*89+row]: Wif, stride-89 padded
  __shared__ __align__(16) float s_g[GB][512];        // full gate pre-activations
  __shared__ __align__(16) float s_fp[NIF][9];        // interface partials [row][2c+b]
  __shared__ float s_bif[NIF];
  __shared__ __align__(16) h1   s_inph[GB][32];       // [x(10), rv(20), pad(2)] fp16
  __shared__ __align__(16) h1   s_h0h[GB][HID];
  __shared__ __align__(16) h1   s_h1h[GB][HID];
  __shared__ __align__(16) h1   s_ctrlh[GB][HID];
  __shared__ __align__(16) float s_ctrl[GB][HID];     // fp32 for epilogue
  __shared__ __align__(16) float s_mem[GB][NC][CW];
  __shared__ float s_rk[GB][CW], s_wk[GB][CW], s_er[GB][CW], s_wv[GB][CW];
  __shared__ float s_mraw[GB][3];
  __shared__ float s_sc[GB][8];     // 0:rs 1:ws 2:fg 3:ga 4:gw 5:m0 6:m1 7:m2
  __shared__ float s_usage[GB][NC], s_u[GB][NC];
  __shared__ float s_prec[GB][NC], s_prec2[GB][NC];
  __shared__ float s_link[GB][NC][NC];
  __shared__ float s_rw[GB][NC], s_ww[GB][NC];
  __shared__ float s_rv[GB][CW];
  __shared__ float s_cw[GB][NC], s_cr[GB][NC], s_fwd[GB][NC], s_bwd[GB][NC];

  const int tid = threadIdx.x;
  const int bg  = blockIdx.x * GB;
  const int r   = tid;              // gate row owned by this thread

  // ---- register weights: Wih0 row (4 f4) + Whh0 full row (16 f4) = 80 VGPRs ----
  float4 A0,A1,A2,A3;
  float4 B0,B1,B2,B3,B4,B5,B6,B7,B8,B9,B10,B11,B12,B13,B14,B15;
  float b0r, b1r;
  {
    const float* p = Wih0 + (size_t)r * (NIN + CW);
    A0=pack8(p); A1=pack8(p+8); A2=pack8(p+16); A3=pack6z(p+24);
    const float* q0 = Whh0 + (size_t)r*HID;
    B0 =pack8(q0);    B1 =pack8(q0+8);  B2 =pack8(q0+16);  B3 =pack8(q0+24);
    B4 =pack8(q0+32); B5 =pack8(q0+40); B6 =pack8(q0+48);  B7 =pack8(q0+56);
    B8 =pack8(q0+64); B9 =pack8(q0+72); B10=pack8(q0+80);  B11=pack8(q0+88);
    B12=pack8(q0+96); B13=pack8(q0+104);B14=pack8(q0+112); B15=pack8(q0+120);
    b0r = b0[r]; b1r = b1[r];
  }

  // ---- LDS weight staging (one-time, transposed, lane-contiguous) ----
  for (int idx = tid; idx < 14*512; idx += BLK) {
    int c = idx >> 9, rr = idx & 511;
    s_wih1T[c][rr] = pack8(Wih1 + (size_t)rr*HID + 8*c);
  }
  for (int idx = tid; idx < 16*NIF; idx += BLK) {
    int j = idx / NIF, q = idx - j*NIF;
    s_wifT[j*89 + q] = pack8(Wif + (size_t)q*HID + 8*j);
  }
  if (tid < NIF) s_bif[tid] = bif[tid];

  // ---- zero-init state ----
  if (tid < GB*HID) { int b=tid>>7, j=tid&127;
    s_h0h[b][j]=(h1)0.f; s_h1h[b][j]=(h1)0.f; s_ctrlh[b][j]=(h1)0.f; s_ctrl[b][j]=0.f; }
  for (int i = tid; i < GB*NC*CW; i += BLK) { int b=i/(NC*CW), e=i%(NC*CW);
    s_mem[b][e/CW][e%CW]=0.f; }
  for (int i = tid; i < GB*NC*NC; i += BLK) { int b=i/(NC*NC), e=i%(NC*NC);
    s_link[b][e/NC][e%NC]=0.f; }
  if (tid < GB*NC) { int b=tid/NC, n=tid%NC;
    s_usage[b][n]=0.f; s_prec[b][n]=0.f; s_rw[b][n]=0.f; s_ww[b][n]=0.f; }
  if (tid < GB*CW) { int b=tid/CW, c=tid%CW; s_rv[b][c]=0.f; }
  if (tid < GB*32) { int b=tid>>5, i=tid&31;
    float v = 0.f;
    if (i < NIN) v = x[((size_t)(bg+b)*NT + 0)*NIN + i];
    s_inph[b][i] = (h1)v;
  }
  float c0r = 0.f, c1r = 0.f;   // LSTM cell states (threads 0..255: b=tid>>7, j=tid&127)
  __syncthreads();

  for (int t = 0; t < NT; ++t) {
    // ---- B: gates0 = [x,rv]@Wih0^T + h0_old@Whh0^T + b0 (full row, regs) ----
    {
      float a0=b0r, a1=b0r, a2=0.f, a3=0.f;
      const float4* Ia = (const float4*)s_inph[0];
      const float4* Ib = (const float4*)s_inph[1];
      LSTEP(A0,0,Ia,Ib) LSTEP(A1,1,Ia,Ib) LSTEP(A2,2,Ia,Ib) LSTEP(A3,3,Ia,Ib)
      const float4* Ha = (const float4*)s_h0h[0];
      const float4* Hb = (const float4*)s_h0h[1];
      LSTEP(B0,0,Ha,Hb)   LSTEP(B1,1,Ha,Hb)   LSTEP(B2,2,Ha,Hb)   LSTEP(B3,3,Ha,Hb)
      LSTEP(B4,4,Ha,Hb)   LSTEP(B5,5,Ha,Hb)   LSTEP(B6,6,Ha,Hb)   LSTEP(B7,7,Ha,Hb)
      LSTEP(B8,8,Ha,Hb)   LSTEP(B9,9,Ha,Hb)   LSTEP(B10,10,Ha,Hb) LSTEP(B11,11,Ha,Hb)
      LSTEP(B12,12,Ha,Hb) LSTEP(B13,13,Ha,Hb) LSTEP(B14,14,Ha,Hb) LSTEP(B15,15,Ha,Hb)
      s_g[0][r] = a0+a2; s_g[1][r] = a1+a3;
    }
    __syncthreads();

    // ---- C: LSTM0 nonlinearity ----
    if (tid < GB*HID) {
      int b = tid>>7, j = tid&127;
      float gi=s_g[b][j], gf=s_g[b][HID+j], gg=s_g[b][2*HID+j], go=s_g[b][3*HID+j];
      float c = sigf(gf)*c0r + sigf(gi)*tanhf(gg);
      c0r = c;
      float h = sigf(go)*tanhf(c);
      s_h0h[b][j] = (h1)h;
    }
    __syncthreads();

    // ---- D: gates1 = h0_new@Wih1^T + h1_old@Whh1^T + b1 ----
    // Wih1 chunks 0..13 from LDS; chunks 14,15 + all Whh1 streamed from d_ws (L2).
    {
      unsigned lnd = 0;
      asm volatile("" : "+v"(lnd));   // launder: defeat LICM hoisting of invariant loads
      const float4* WS = (const float4*)((const char*)wsT + lnd);
      float a0=b1r, a1=b1r, a2=0.f, a3=0.f;
      const float4* Ha = (const float4*)s_h0h[0];
      const float4* Hb = (const float4*)s_h0h[1];
      const float4* Ga = (const float4*)s_h1h[0];
      const float4* Gb = (const float4*)s_h1h[1];
      float4 t0 = WS[16*512 + tid];        // Wih1 c14
      float4 t1 = WS[17*512 + tid];        // Wih1 c15
      float4 u0 = WS[0*512 + tid];         // Whh1 c0
      float4 u1 = WS[1*512 + tid];         // Whh1 c1
      { float4 w=s_wih1T[ 0][r]; LSTEP(w, 0,Ha,Hb) }
      { float4 w=s_wih1T[ 1][r]; LSTEP(w, 1,Ha,Hb) }
      { float4 w=s_wih1T[ 2][r]; LSTEP(w, 2,Ha,Hb) }
      { float4 w=s_wih1T[ 3][r]; LSTEP(w, 3,Ha,Hb) }
      { float4 w=s_wih1T[ 4][r]; LSTEP(w, 4,Ha,Hb) }
      { float4 w=s_wih1T[ 5][r]; LSTEP(w, 5,Ha,Hb) }
      { float4 w=s_wih1T[ 6][r]; LSTEP(w, 6,Ha,Hb) }
      { float4 w=s_wih1T[ 7][r]; LSTEP(w, 7,Ha,Hb) }
      { float4 w=s_wih1T[ 8][r]; LSTEP(w, 8,Ha,Hb) }
      { float4 w=s_wih1T[ 9][r]; LSTEP(w, 9,Ha,Hb) }
      { float4 w=s_wih1T[10][r]; LSTEP(w,10,Ha,Hb) }
      { float4 w=s_wih1T[11][r]; LSTEP(w,11,Ha,Hb) }
      { float4 w=s_wih1T[12][r]; LSTEP(w,12,Ha,Hb) }
      { float4 w=s_wih1T[13][r]; LSTEP(w,13,Ha,Hb) }
      LSTEP(t0,14,Ha,Hb) LSTEP(t1,15,Ha,Hb)
      t0 = WS[ 2*512+tid]; t1 = WS[ 3*512+tid];
      LSTEP(u0, 0,Ga,Gb) LSTEP(u1, 1,Ga,Gb)
      u0 = WS[ 4*512+tid]; u1 = WS[ 5*512+tid];
      LSTEP(t0, 2,Ga,Gb) LSTEP(t1, 3,Ga,Gb)
      t0 = WS[ 6*512+tid]; t1 = WS[ 7*512+tid];
      LSTEP(u0, 4,Ga,Gb) LSTEP(u1, 5,Ga,Gb)
      u0 = WS[ 8*512+tid]; u1 = WS[ 9*512+tid];
      LSTEP(t0, 6,Ga,Gb) LSTEP(t1, 7,Ga,Gb)
      t0 = WS[10*512+tid]; t1 = WS[11*512+tid];
      LSTEP(u0, 8,Ga,Gb) LSTEP(u1, 9,Ga,Gb)
      u0 = WS[12*512+tid]; u1 = WS[13*512+tid];
      LSTEP(t0,10,Ga,Gb) LSTEP(t1,11,Ga,Gb)
      t0 = WS[14*512+tid]; t1 = WS[15*512+tid];
      LSTEP(u0,12,Ga,Gb) LSTEP(u1,13,Ga,Gb)
      LSTEP(t0,14,Ga,Gb) LSTEP(t1,15,Ga,Gb)
      s_g[0][r] = a0+a2; s_g[1][r] = a1+a3;
    }
    __syncthreads();

    // ---- E: LSTM1 nonlinearity + ctrl clip ----
    if (tid < GB*HID) {
      int b = tid>>7, j = tid&127;
      float gi=s_g[b][j], gf=s_g[b][HID+j], gg=s_g[b][2*HID+j], go=s_g[b][3*HID+j];
      float c = sigf(gf)*c1r + sigf(gi)*tanhf(gg);
      c1r = c;
      float h = sigf(go)*tanhf(c);
      float ctl = fminf(fmaxf(h, -20.f), 20.f);
      s_h1h[b][j] = (h1)h;
      s_ctrl[b][j] = ctl;
      s_ctrlh[b][j] = (h1)ctl;
    }
    __syncthreads();

    // ---- F: interface partials, 4 threads per row (LDS weights, lane-contiguous) ----
    if (tid < 4*NIF) {
      int q = tid >> 2, c = tid & 3;
      float a0=0.f, a1=0.f, a2=0.f, a3=0.f;
      const float4* Ca = (const float4*)s_ctrlh[0];
      const float4* Cb = (const float4*)s_ctrlh[1];
      float4 w0 = s_wifT[(4*c+0)*89 + q];
      float4 w1 = s_wifT[(4*c+1)*89 + q];
      float4 w2 = s_wifT[(4*c+2)*89 + q];
      float4 w3 = s_wifT[(4*c+3)*89 + q];
      LSTEP(w0, 4*c+0, Ca, Cb) LSTEP(w1, 4*c+1, Ca, Cb)
      LSTEP(w2, 4*c+2, Ca, Cb) LSTEP(w3, 4*c+3, Ca, Cb)
      s_fp[q][2*c  ] = a0+a2;
      s_fp[q][2*c+1] = a1+a3;
    }
    __syncthreads();

    // ---- W0: F-combine + all DNC memory ops, wave 0 only, LDS fences not barriers ----
    if (tid < 64) {
      const int lane = tid;
      // prefetch next x early (latency hidden under combine/H..L)
      float xv = 0.f;
      if (lane >= GB*CW && lane < GB*CW + GB*NIN && (t+1) < NT) {
        int q = lane - GB*CW, b = q/NIN, i = q%NIN;
        xv = x[((size_t)(bg+b)*NT + (t+1))*NIN + i];
      }

      // F-combine: xi = bif + sum of 4 partials, fused transforms
      #pragma unroll
      for (int e = lane; e < 2*NIF; e += 64) {
        int b = e & 1, q = e >> 1;
        float a = s_bif[q];
        #pragma unroll
        for (int c = 0; c < 4; ++c) a += s_fp[q][2*c+b];
        if      (q < 20)  s_rk[b][q]    = tanhf(a);
        else if (q == 20) s_sc[b][0]    = splus(a);
        else if (q < 41)  s_wk[b][q-21] = tanhf(a);
        else if (q == 41) s_sc[b][1]    = splus(a);
        else if (q < 62)  s_er[b][q-42] = sigf(a);
        else if (q < 82)  s_wv[b][q-62] = tanhf(a);
        else if (q == 82) s_sc[b][2]    = sigf(a);
        else if (q == 83) s_sc[b][3]    = sigf(a);
        else if (q == 84) s_sc[b][4]    = sigf(a);
        else              s_mraw[b][q-85] = a;
      }
      LDSFENCE();

      // H: usage/psi + write-content sims + modes softmax
      if (lane < GB*NC) {
        int b = lane/NC, n = lane%NC;
        float fg = s_sc[b][2];
        float psi = 1.f - fg * s_rw[b][n];
        float u = s_usage[b][n], w = s_ww[b][n];
        u = (u + w - u*w) * psi;
        s_usage[b][n] = u;
        s_u[b][n] = 1e-6f + (1.0f - 1e-6f) * u;
        float dot=0.f, mn=0.f, kn=0.f;
        #pragma unroll
        for (int c = 0; c < CW; ++c) {
          float m = s_mem[b][n][c], k = s_wk[b][c];
          dot += k*m; mn += m*m; kn += k*k;
        }
        s_cw[b][n] = dot / (sqrtf(kn)*sqrtf(mn) + 1e-6f) * s_sc[b][1];
      } else if (lane < GB*NC + GB) {
        int b = lane - GB*NC;
        float m0=s_mraw[b][0], m1=s_mraw[b][1], m2=s_mraw[b][2];
        float mm = fmaxf(m0, fmaxf(m1, m2));
        float e0=expf(m0-mm), e1=expf(m1-mm), e2=expf(m2-mm);
        float es = e0+e1+e2;
        s_sc[b][5]=e0/es; s_sc[b][6]=e1/es; s_sc[b][7]=e2/es;
      }
      LDSFENCE();

      // I: cw softmax + rank-based allocation + new ww
      if (lane < GB*NC) {
        int b = lane/NC, n = lane%NC;
        float mx = -1e30f;
        #pragma unroll
        for (int m = 0; m < NC; ++m) mx = fmaxf(mx, s_cw[b][m]);
        float sm = 0.f;
        #pragma unroll
        for (int m = 0; m < NC; ++m) sm += expf(s_cw[b][m]-mx);
        float cwv = expf(s_cw[b][n]-mx) / sm;
        float un = s_u[b][n];
        float excl = 1.f;
        #pragma unroll
        for (int m = 0; m < NC; ++m) {
          float um = s_u[b][m];
          bool before = (um < un) || (um == un && m < n);
          excl *= before ? um : 1.f;
        }
        float alloc = (1.f - un) * excl;
        float ga = s_sc[b][3], gw = s_sc[b][4];
        s_ww[b][n] = gw * (ga*alloc + (1.f-ga)*cwv);
      }
      LDSFENCE();

      // J: memory write + link update (old prec) + prec2
      #pragma unroll
      for (int e = lane; e < GB*NC*CW; e += 64) {
        int b = e/(NC*CW), rr = (e%(NC*CW))/CW, c = e%CW;
        float w = s_ww[b][rr];
        s_mem[b][rr][c] = s_mem[b][rr][c] * (1.f - w*s_er[b][c]) + w*s_wv[b][c];
      }
      #pragma unroll
      for (int e = lane; e < GB*NC*NC; e += 64) {
        int b = e/(NC*NC), i = (e%(NC*NC))/NC, j = e%NC;
        float wi = s_ww[b][i], wj = s_ww[b][j];
        float l = (1.f - wi - wj)*s_link[b][i][j] + wi*s_prec[b][j];
        s_link[b][i][j] = (i==j) ? 0.f : l;
      }
      if (lane < GB*NC) {
        int b = lane/NC, n = lane%NC;
        float sw2 = 0.f;
        #pragma unroll
        for (int m = 0; m < NC; ++m) sw2 += s_ww[b][m];
        s_prec2[b][n] = (1.f - sw2)*s_prec[b][n] + s_ww[b][n];
      }
      LDSFENCE();

      // K: commit prec, fwd/bwd on new link, read-content sims on new mem
      if (lane < GB*NC) {
        int b = lane/NC, m = lane%NC;
        s_prec[b][m] = s_prec2[b][m];
        float a = 0.f;
        #pragma unroll
        for (int n = 0; n < NC; ++n) a += s_rw[b][n]*s_link[b][m][n];
        s_fwd[b][m] = a;
      } else if (lane < 2*GB*NC) {
        int q = lane - GB*NC, b = q/NC, m = q%NC;
        float a = 0.f;
        #pragma unroll
        for (int n = 0; n < NC; ++n) a += s_rw[b][n]*s_link[b][n][m];
        s_bwd[b][m] = a;
      } else if (lane < 3*GB*NC) {
        int q = lane - 2*GB*NC, b = q/NC, n = q%NC;
        float dot=0.f, mn=0.f, kn=0.f;
        #pragma unroll
        for (int c = 0; c < CW; ++c) {
          float m = s_mem[b][n][c], k = s_rk[b][c];
          dot += k*m; mn += m*m; kn += k*k;
        }
        s_cr[b][n] = dot/(sqrtf(kn)*sqrtf(mn)+1e-6f) * s_sc[b][0];
      }
      LDSFENCE();

      // L: cr softmax + new read weights
      if (lane < GB*NC) {
        int b = lane/NC, n = lane%NC;
        float mx = -1e30f;
        #pragma unroll
        for (int m = 0; m < NC; ++m) mx = fmaxf(mx, s_cr[b][m]);
        float sm = 0.f;
        #pragma unroll
        for (int m = 0; m < NC; ++m) sm += expf(s_cr[b][m]-mx);
        float cr = expf(s_cr[b][n]-mx)/sm;
        s_rw[b][n] = s_sc[b][5]*s_bwd[b][n] + s_sc[b][6]*cr + s_sc[b][7]*s_fwd[b][n];
      }
      LDSFENCE();

      // M: read vectors + pack next-step input (x part from prefetch)
      if (lane < GB*CW) {
        int b = lane/CW, c = lane%CW;
        float a = 0.f;
        #pragma unroll
        for (int n = 0; n < NC; ++n) a += s_rw[b][n]*s_mem[b][n][c];
        s_rv[b][c] = a;
        s_inph[b][NIN + c] = (h1)a;
      } else if (lane < GB*CW + GB*NIN && (t+1) < NT) {
        int q = lane - GB*CW, b = q/NIN, i = q%NIN;
        s_inph[b][i] = (h1)xv;
      }
    }
    __syncthreads();
  }

  // ---- epilogue: y_T = [ctrl, rv] @ Wout^T + bout ----
  if (tid < GB*NOUT) {
    int b = tid/NOUT, o = tid%NOUT;
    float a = bout[o];
    const float* Wr = Wout + o*(HID+CW);
    #pragma unroll 4
    for (int k = 0; k < HID; ++k) a += Wr[k]*s_ctrl[b][k];
    #pragma unroll
    for (int c = 0; c < CW; ++c) a += Wr[HID+c]*s_rv[b][c];
    out[(size_t)(bg+b)*NOUT + o] = a;
  }
}

extern "C" void kernel_launch(void* const* d_in, const int* in_sizes, int n_in,
                              void* d_out, int out_size, void* d_ws, size_t ws_size,
                              hipStream_t stream) {
  (void)in_sizes; (void)n_in; (void)out_size; (void)ws_size;
  const float* x    = (const float*)d_in[0];
  const float* Wih0 = (const float*)d_in[1];
  const float* Whh0 = (const float*)d_in[2];
  const float* b0   = (const float*)d_in[3];
  const float* Wih1 = (const float*)d_in[4];
  const float* Whh1 = (const float*)d_in[5];
  const float* b1   = (const float*)d_in[6];
  const float* Wif  = (const float*)d_in[7];
  const float* bif  = (const float*)d_in[8];
  const float* Wout = (const float*)d_in[9];
  const float* bout = (const float*)d_in[10];
  float* out = (float*)d_out;
  float4* ws = (float4*)d_ws;

  dnc_pack_kernel<<<dim3(36), dim3(256), 0, stream>>>(Wih1, Whh1, ws);
  dnc_stream_kernel<<<dim3(NB/GB), dim3(BLK), 0, stream>>>(
      x, Wih0, Whh0, b0, Wih1, Whh1, b1, Wif, bif, Wout, bout, ws, out);
}